// Round 2
// baseline (30478.015 us; speedup 1.0000x reference)
//
#include <hip/hip_runtime.h>
#include <math.h>

#pragma clang fp contract(off)

#define NB 2048
#define NC 1000
#define NK 2048
#define ROWS 4               // rows per persistent block
#define NBLK (NB / ROWS)     // 512 blocks = 2 blocks/CU * 256 CUs (guaranteed co-resident)

// ---------------- GEMM: fp32 fold-left ascending-k with K-panel folds of PC chunks ------
__global__ __launch_bounds__(256) void k_gemm(const float* __restrict__ x,
                                              const float* __restrict__ W,
                                              const float* __restrict__ bias,
                                              float* __restrict__ z, int PC) {
    __shared__ float As[16][64];
    __shared__ float Bs[16][64];
    const int tid = threadIdx.x;
    const int m0 = blockIdx.y * 64, n0 = blockIdx.x * 64;
    const int tx = tid & 15, ty = tid >> 4;
    float accT[4][4];
    float accB[4][4];
#pragma unroll
    for (int i = 0; i < 4; i++)
#pragma unroll
        for (int j = 0; j < 4; j++) { accT[i][j] = 0.0f; accB[i][j] = 0.0f; }

    for (int kb = 0; kb < 128; kb++) {
        if (PC > 0 && kb > 0 && (kb % PC) == 0) {
#pragma unroll
            for (int i = 0; i < 4; i++)
#pragma unroll
                for (int j = 0; j < 4; j++) { accT[i][j] += accB[i][j]; accB[i][j] = 0.0f; }
        }
        const int k0 = kb * 16;
        {
            int row = tid >> 2, kg = tid & 3;
            const float4 a = *(const float4*)(x + (size_t)(m0 + row) * NK + k0 + kg * 4);
            As[kg * 4 + 0][row] = a.x;
            As[kg * 4 + 1][row] = a.y;
            As[kg * 4 + 2][row] = a.z;
            As[kg * 4 + 3][row] = a.w;
        }
        {
            int rowk = tid >> 4, c4 = tid & 15;
            int cbase = n0 + c4 * 4;
            const float* wp = W + (size_t)(k0 + rowk) * NC + cbase;
#pragma unroll
            for (int j = 0; j < 4; j++)
                Bs[rowk][c4 * 4 + j] = (cbase + j < NC) ? wp[j] : 0.0f;
        }
        __syncthreads();
#pragma unroll
        for (int kk = 0; kk < 16; kk++) {
            float a[4], bb[4];
#pragma unroll
            for (int i = 0; i < 4; i++) a[i] = As[kk][ty * 4 + i];
#pragma unroll
            for (int j = 0; j < 4; j++) bb[j] = Bs[kk][tx * 4 + j];
#pragma unroll
            for (int i = 0; i < 4; i++)
#pragma unroll
                for (int j = 0; j < 4; j++) accB[i][j] = fmaf(a[i], bb[j], accB[i][j]);
        }
        __syncthreads();
    }
#pragma unroll
    for (int i = 0; i < 4; i++) {
        int r = m0 + ty * 4 + i;
#pragma unroll
        for (int j = 0; j < 4; j++) {
            int c = n0 + tx * 4 + j;
            if (c < NC) {
                float s = accT[i][j] + accB[i][j];
                z[(size_t)r * NC + c] = s + bias[c];
            }
        }
    }
}

// ---------------- per-row stats ----------------
__global__ __launch_bounds__(256) void k_rowstats(const float* __restrict__ z,
                                                  int* __restrict__ y,
                                                  float* __restrict__ ptrg,
                                                  float* __restrict__ se,
                                                  float* __restrict__ rm,
                                                  int* __restrict__ am) {
    __shared__ float sv[256];
    __shared__ int si[256];
    const int tid = threadIdx.x, row = blockIdx.x;
    const float* zr = z + (size_t)row * NC;
    float bv = -INFINITY;
    int bi = 0x7fffffff;
    for (int c = tid; c < NC; c += 256) {
        float zz = zr[c];
        if (zz > bv) { bv = zz; bi = c; }
    }
    sv[tid] = bv; si[tid] = bi;
    __syncthreads();
    for (int s = 128; s > 0; s >>= 1) {
        if (tid < s) {
            float v2 = sv[tid + s]; int i2 = si[tid + s];
            if (v2 > sv[tid] || (v2 == sv[tid] && i2 < si[tid])) { sv[tid] = v2; si[tid] = i2; }
        }
        __syncthreads();
    }
    const float rmx = sv[0];
    const int amx = si[0];
    __syncthreads();
    float sl = 0.0f;
    for (int c = tid; c < NC; c += 256) sl += expf(zr[c] - rmx);
    sv[tid] = sl;
    __syncthreads();
    for (int s = 128; s > 0; s >>= 1) {
        if (tid < s) sv[tid] += sv[tid + s];
        __syncthreads();
    }
    if (tid == 0) {
        float s0 = sv[0];
        y[row] = amx; ptrg[row] = 1.0f / s0;
        se[row] = s0; rm[row] = rmx; am[row] = amx;
    }
}

__global__ void k_hist(const int* __restrict__ y, int* __restrict__ cnt) {
    int i = blockIdx.x * 256 + threadIdx.x;
    if (i < NB) atomicAdd(&cnt[y[i]], 1);
}
__global__ __launch_bounds__(1024) void k_group(const int* __restrict__ y,
                                                const int* __restrict__ cnt,
                                                int* __restrict__ off,
                                                int* __restrict__ pos,
                                                int* __restrict__ jidx) {
    __shared__ int s[1024];
    const int tid = threadIdx.x;
    int myc = (tid < NC) ? cnt[tid] : 0;
    s[tid] = myc;
    __syncthreads();
    for (int d = 1; d < 1024; d <<= 1) {
        int add = (tid >= d) ? s[tid - d] : 0;
        __syncthreads();
        s[tid] += add;
        __syncthreads();
    }
    if (tid < NC) {
        int excl = s[tid] - myc;
        off[tid] = excl;
        pos[tid] = excl;
    }
    if (tid == 0) off[NC] = NB;
    __syncthreads();
    for (int j = tid; j < NB; j += 1024) {
        int c = y[j];
        int p = atomicAdd(&pos[c], 1);
        jidx[p] = j;
    }
}

// tz/tu only; u init lives in registers inside k_adam (reads z directly)
__global__ __launch_bounds__(256) void k_preptz(const float* __restrict__ z,
                                                const int* __restrict__ cnt,
                                                float* __restrict__ tz,
                                                float* __restrict__ tu) {
    __shared__ float sv[256];
    const int tid = threadIdx.x, row = blockIdx.x;
    const float* zr = z + (size_t)row * NC;
    float tm = -1000.0f;
    for (int c = tid; c < NC; c += 256) {
        float zz = zr[c];
        if (cnt[c] == 0) tm = fmaxf(tm, zz);
    }
    sv[tid] = tm;
    __syncthreads();
    for (int s = 128; s > 0; s >>= 1) {
        if (tid < s) sv[tid] = fmaxf(sv[tid], sv[tid + s]);
        __syncthreads();
    }
    if (tid == 0) { tz[row] = sv[0]; tu[row] = sv[0]; }
}

__global__ __launch_bounds__(256) void k_thr(const float* __restrict__ z,
                                             const float* __restrict__ tz,
                                             const int* __restrict__ y,
                                             const int* __restrict__ jidx,
                                             float* __restrict__ ThrG) {
    const int tid = threadIdx.x, a = blockIdx.x;
    const float PIF = 3.14159265358979323846f;
    const float* zr = z + (size_t)a * NC;
    for (int p = tid; p < NB; p += 256) {
        int j = jidx[p];
        int c = y[j];
        float L = zr[c] - tz[j];
        float q = L / 6.0f;
        float fq = floorf(q);
        float fh = fq + 0.5f;
        float latr = fh * 6.0f;
        float d1 = L - latr;
        float d2 = 2.0f * d1;
        float d3 = d2 / 6.0f;
        float d4 = 1.0f - d3;
        float d5 = PIF * d4;
        float sn = sinf(d5);
        float p6 = 6.0f * sn;
        float thr = L - p6;
        ThrG[(size_t)a * NB + p] = thr;
    }
}

// ---------------- software grid barrier (all NBLK blocks guaranteed co-resident) --------
__device__ __forceinline__ void gridbar(int* __restrict__ bar, int t) {
    __syncthreads();
    if (threadIdx.x == 0) {
        __threadfence();                               // release: publish this block's writes
        atomicAdd(&bar[t], 1);                         // device-scope by default
        while (__hip_atomic_load(&bar[t], __ATOMIC_RELAXED, __HIP_MEMORY_SCOPE_AGENT) < NBLK) {
            __builtin_amdgcn_s_sleep(2);
        }
        __threadfence();                               // acquire: invalidate stale caches
    }
    __syncthreads();
}

// ---------------- all 100 Adam steps in one persistent kernel ----------------
// u,m,v register-resident; arithmetic sequence identical to the round-0 per-step kernel.
__global__ __launch_bounds__(256, 2) void k_adam(
    const float* __restrict__ z0,
    float* __restrict__ uout,
    const float* __restrict__ ThrG,
    const float* __restrict__ ptrg,
    const int* __restrict__ cnt,
    const int* __restrict__ off,
    const int* __restrict__ jidx,
    float* __restrict__ seA, float* __restrict__ rmA,
    float* __restrict__ tuA, int* __restrict__ amA,
    float* __restrict__ seB, float* __restrict__ rmB,
    float* __restrict__ tuB, int* __restrict__ amB,
    const float* __restrict__ bcT,
    int* __restrict__ bar) {
    __shared__ float tuG[NB];
    __shared__ float sv[256];
    __shared__ int si[256];
    __shared__ float sv4[ROWS][256];   // joint per-row trees (batched syncthreads)
    __shared__ int si4[ROWS][256];
    __shared__ float tv4[ROWS][256];
    __shared__ float fbc[2];
    __shared__ int ibc[1];
    const int tid = threadIdx.x;
    const int row0 = blockIdx.x * ROWS;
    const float B1F = 0.9f;
    const float C1 = (float)(1.0 - 0.9);
    const float B2F = 0.999f;
    const float C2 = (float)(1.0 - 0.999);

    float U[ROWS][4], M[ROWS][4], V[ROWS][4];
#pragma unroll
    for (int r = 0; r < ROWS; r++) {
        const size_t base = (size_t)(row0 + r) * NC;
#pragma unroll
        for (int k2 = 0; k2 < 4; k2++) {
            int c = tid + k2 * 256;
            U[r][k2] = (c < NC) ? z0[base + c] : 0.0f;
            M[r][k2] = 0.0f;
            V[r][k2] = 0.0f;
        }
    }

    for (int t = 1; t <= 100; t++) {
        const bool odd = (t & 1);
        const float* seO = odd ? seA : seB;
        const float* rmO = odd ? rmA : rmB;
        const float* tuO = odd ? tuA : tuB;
        const int*   amO = odd ? amA : amB;
        float* seN = odd ? seB : seA;
        float* rmN = odd ? rmB : rmA;
        float* tuN = odd ? tuB : tuA;
        int*   amN = odd ? amB : amA;
        const float bc1 = bcT[2 * (t - 1)];
        const float bc2 = bcT[2 * (t - 1) + 1];

        // ---- phase 1: gather tu, global pmax/istar, s2 (identical sequences) ----
        for (int p = tid; p < NB; p += 256) tuG[p] = tuO[jidx[p]];

        float bv = -INFINITY;
        int bi = 0x7fffffff;
        for (int i = tid; i < NB; i += 256) {
            float pp = 1.0f / seO[i];
            if (pp > bv || (pp == bv && i < bi)) { bv = pp; bi = i; }
        }
        sv[tid] = bv; si[tid] = bi;
        __syncthreads();
        for (int s = 128; s > 0; s >>= 1) {
            if (tid < s) {
                float v2 = sv[tid + s]; int i2 = si[tid + s];
                if (v2 > sv[tid] || (v2 == sv[tid] && i2 < si[tid])) { sv[tid] = v2; si[tid] = i2; }
            }
            __syncthreads();
        }
        const float pmax = sv[0];
        const int istar = si[0];
        __syncthreads();
        float s2l = 0.0f;
        for (int i = tid; i < NB; i += 256) {
            float d = pmax - ptrg[i];
            s2l += (d >= 0.0f) ? 1.0f : -1.0f;
        }
        sv[tid] = s2l;
        __syncthreads();
        for (int s = 128; s > 0; s >>= 1) {
            if (tid < s) sv[tid] += sv[tid + s];
            __syncthreads();
        }
        const float s2 = sv[0];
        if (tid == 0) {
            fbc[0] = seO[istar];
            fbc[1] = rmO[istar];
            ibc[0] = amO[istar];
        }
        __syncthreads();
        const float se_i = fbc[0], rm_i = fbc[1];
        const int jstar = ibc[0];
        const float Kf = 5.0f * (2048.0f * s2);
        const float coef = Kf * pmax;

        // ---- phase 2: per-row gradient + Adam update (registers) ----
        float nmaxR[ROWS], ntopR[ROWS];
        int nidxR[ROWS];
#pragma unroll
        for (int r = 0; r < ROWS; r++) {
            const int row = row0 + r;
            const bool ig2 = (row == istar);
            const size_t tbase = (size_t)row * NB;
            float nmax = -INFINITY;
            int nidx = 0x7fffffff;
            float ntop = -1000.0f;
#pragma unroll
            for (int k2 = 0; k2 < 4; k2++) {
                int c = tid + k2 * 256;
                if (c < NC) {
                    float u0 = U[r][k2];
                    float mm = M[r][k2];
                    float vv = V[r][k2];
                    int cn = cnt[c];
                    int p0 = off[c], p1 = off[c + 1];
                    float g = 0.0f;
                    for (int p = p0; p < p1; p++) {
                        float marg = u0 - tuG[p];
                        float diff = marg - ThrG[tbase + p];
                        g += (diff >= 0.0f) ? 1.0f : -1.0f;
                    }
                    if (ig2) {
                        float e = expf(u0 - rm_i);
                        float S = e / se_i;
                        float dlt = ((c == jstar) ? 1.0f : 0.0f) - S;
                        float t2v = coef * dlt;
                        g = g + t2v;
                    }
                    float t1m = B1F * mm;
                    float t2m = C1 * g;
                    mm = t1m + t2m;
                    float gg1 = C2 * g;
                    float gg2 = gg1 * g;
                    float t1v = B2F * vv;
                    vv = t1v + gg2;
                    float mh = mm / bc1;
                    float vh = vv / bc2;
                    float num = 0.1f * mh;
                    float sq = sqrtf(vh);
                    float den = sq + 1e-8f;
                    float qq = num / den;
                    u0 = u0 - qq;
                    U[r][k2] = u0;
                    M[r][k2] = mm;
                    V[r][k2] = vv;
                    if (u0 > nmax || (u0 == nmax && c < nidx)) { nmax = u0; nidx = c; }
                    if (cn == 0) ntop = fmaxf(ntop, u0);
                }
            }
            nmaxR[r] = nmax; nidxR[r] = nidx; ntopR[r] = ntop;
        }

        // ---- phase 3: joint argmax + masked-max trees (per-row op order unchanged) ----
        __syncthreads();
#pragma unroll
        for (int r = 0; r < ROWS; r++) {
            sv4[r][tid] = nmaxR[r]; si4[r][tid] = nidxR[r]; tv4[r][tid] = ntopR[r];
        }
        __syncthreads();
        for (int s = 128; s > 0; s >>= 1) {
            if (tid < s) {
#pragma unroll
                for (int r = 0; r < ROWS; r++) {
                    float v2 = sv4[r][tid + s]; int i2 = si4[r][tid + s];
                    if (v2 > sv4[r][tid] || (v2 == sv4[r][tid] && i2 < si4[r][tid])) {
                        sv4[r][tid] = v2; si4[r][tid] = i2;
                    }
                    tv4[r][tid] = fmaxf(tv4[r][tid], tv4[r][tid + s]);
                }
            }
            __syncthreads();
        }
        float rmN_[ROWS], tuN_[ROWS];
        int amN_[ROWS];
#pragma unroll
        for (int r = 0; r < ROWS; r++) {
            rmN_[r] = sv4[r][0]; amN_[r] = si4[r][0]; tuN_[r] = tv4[r][0];
        }
        __syncthreads();

        // ---- phase 4: joint sum tree for sel (per-row pairwise order identical) ----
#pragma unroll
        for (int r = 0; r < ROWS; r++) {
            float sel = 0.0f;
#pragma unroll
            for (int k2 = 0; k2 < 4; k2++) {
                int c = tid + k2 * 256;
                if (c < NC) sel += expf(U[r][k2] - rmN_[r]);
            }
            sv4[r][tid] = sel;
        }
        __syncthreads();
        for (int s = 128; s > 0; s >>= 1) {
            if (tid < s) {
#pragma unroll
                for (int r = 0; r < ROWS; r++) sv4[r][tid] += sv4[r][tid + s];
            }
            __syncthreads();
        }
        if (tid == 0) {
#pragma unroll
            for (int r = 0; r < ROWS; r++) {
                seN[row0 + r] = sv4[r][0];
                rmN[row0 + r] = rmN_[r];
                tuN[row0 + r] = tuN_[r];
                amN[row0 + r] = amN_[r];
            }
        }

        gridbar(bar, t - 1);
    }

#pragma unroll
    for (int r = 0; r < ROWS; r++) {
        const size_t base = (size_t)(row0 + r) * NC;
#pragma unroll
        for (int k2 = 0; k2 < 4; k2++) {
            int c = tid + k2 * 256;
            if (c < NC) uout[base + c] = U[r][k2];
        }
    }
}

// ---------------- fuse: out = A + clamp(median5(A,P1..P4) - A, +-0.08) ----------------
__global__ void k_fuse5(const float* __restrict__ a, const float* __restrict__ p1,
                        const float* __restrict__ p2, const float* __restrict__ p3,
                        const float* __restrict__ p4, float* __restrict__ out, int n) {
    const float CL = 0.08f;
    int i = blockIdx.x * 256 + threadIdx.x;
    if (i < n) {
        float v0 = a[i], v1 = p1[i], v2 = p2[i], v3 = p3[i], v4 = p4[i];
        float vv[5] = {v0, v1, v2, v3, v4};
#pragma unroll
        for (int k = 1; k < 5; k++) {
            float key = vv[k];
            int j = k - 1;
            while (j >= 0 && vv[j] > key) { vv[j + 1] = vv[j]; j--; }
            vv[j + 1] = key;
        }
        float med = vv[2];
        float d = med - v0;
        d = fminf(fmaxf(d, -CL), CL);
        out[i] = v0 + d;
    }
}

extern "C" void kernel_launch(void* const* d_in, const int* in_sizes, int n_in,
                              void* d_out, int out_size, void* d_ws, size_t ws_size,
                              hipStream_t stream) {
    (void)in_sizes; (void)n_in; (void)out_size; (void)ws_size;
    const float* x = (const float*)d_in[0];
    const float* W = (const float*)d_in[1];
    const float* bias = (const float*)d_in[2];
    float* out = (float*)d_out;

    const size_t NE = (size_t)NB * NC;
    float* zm   = (float*)d_ws;
    float* t0   = zm + NE;                  // 5 trajectory buffers
    float* t1   = t0 + NE;
    float* t2   = t1 + NE;
    float* t3   = t2 + NE;
    float* t4   = t3 + NE;
    float* ThrG = t4 + NE;                  // 2048*2048
    float* tz   = ThrG + (size_t)NB * NB;
    float* ptrg = tz + NB;
    float* seA  = ptrg + NB;
    float* rmA  = seA + NB;
    float* tuA  = rmA + NB;
    float* seB  = tuA + NB;
    float* rmB  = seB + NB;
    float* tuB  = rmB + NB;
    float* bcT  = tuB + NB;                 // 200 floats (bias-correction table)
    int* amA  = (int*)(bcT + 256);
    int* amB  = amA + NB;
    int* yv   = amB + NB;
    int* jidx = yv + NB;
    int* cnt  = jidx + NB;
    int* off  = cnt + 1024;
    int* pos  = off + 1024;
    int* bar  = pos + 1024;                 // 128 ints: per-step barrier counters

    // host-side bias corrections, exact same powf as round-0 (host libm)
    static float h_bc[200];
    static int bc_init = 0;
    if (!bc_init) {
        for (int t = 1; t <= 100; t++) {
            h_bc[2 * (t - 1)]     = 1.0f - powf(0.9f, (float)t);
            h_bc[2 * (t - 1) + 1] = 1.0f - powf(0.999f, (float)t);
        }
        bc_init = 1;
    }
    hipMemcpyAsync(bcT, h_bc, 200 * sizeof(float), hipMemcpyHostToDevice, stream);

    float* traj[5] = {t0, t1, t2, t3, t4};
    const int PCs[5] = {0, 32, 24, 16, 10};   // monolithic, Kc=512,384,256,160
    const int nblk = (int)((NE + 255) / 256);

    for (int pass = 0; pass < 5; pass++) {
        k_gemm<<<dim3(16, 32), 256, 0, stream>>>(x, W, bias, zm, PCs[pass]);
        hipMemsetAsync(cnt, 0, 1024 * sizeof(int), stream);
        hipMemsetAsync(bar, 0, 128 * sizeof(int), stream);
        k_rowstats<<<NB, 256, 0, stream>>>(zm, yv, ptrg, seA, rmA, amA);
        k_hist<<<8, 256, 0, stream>>>(yv, cnt);
        k_group<<<1, 1024, 0, stream>>>(yv, cnt, off, pos, jidx);
        k_preptz<<<NB, 256, 0, stream>>>(zm, cnt, tz, tuA);
        k_thr<<<NB, 256, 0, stream>>>(zm, tz, yv, jidx, ThrG);

        k_adam<<<NBLK, 256, 0, stream>>>(zm, traj[pass], ThrG, ptrg, cnt, off, jidx,
                                         seA, rmA, tuA, amA, seB, rmB, tuB, amB,
                                         bcT, bar);
    }

    k_fuse5<<<nblk, 256, 0, stream>>>(t0, t1, t2, t3, t4, out, (int)NE);
}

// Round 3
// 17619.710 us; speedup vs baseline: 1.7298x; 1.7298x over previous
//
#include <hip/hip_runtime.h>
#include <math.h>

#pragma clang fp contract(off)

#define NB 2048
#define NC 1000
#define NK 2048
#define NBLK 2048            // one block per row; 8 blocks/CU * 256 CUs co-resident

// ---------------- GEMM: fp32 fold-left ascending-k with K-panel folds of PC chunks ------
__global__ __launch_bounds__(256) void k_gemm(const float* __restrict__ x,
                                              const float* __restrict__ W,
                                              const float* __restrict__ bias,
                                              float* __restrict__ z, int PC) {
    __shared__ float As[16][64];
    __shared__ float Bs[16][64];
    const int tid = threadIdx.x;
    const int m0 = blockIdx.y * 64, n0 = blockIdx.x * 64;
    const int tx = tid & 15, ty = tid >> 4;
    float accT[4][4];
    float accB[4][4];
#pragma unroll
    for (int i = 0; i < 4; i++)
#pragma unroll
        for (int j = 0; j < 4; j++) { accT[i][j] = 0.0f; accB[i][j] = 0.0f; }

    for (int kb = 0; kb < 128; kb++) {
        if (PC > 0 && kb > 0 && (kb % PC) == 0) {
#pragma unroll
            for (int i = 0; i < 4; i++)
#pragma unroll
                for (int j = 0; j < 4; j++) { accT[i][j] += accB[i][j]; accB[i][j] = 0.0f; }
        }
        const int k0 = kb * 16;
        {
            int row = tid >> 2, kg = tid & 3;
            const float4 a = *(const float4*)(x + (size_t)(m0 + row) * NK + k0 + kg * 4);
            As[kg * 4 + 0][row] = a.x;
            As[kg * 4 + 1][row] = a.y;
            As[kg * 4 + 2][row] = a.z;
            As[kg * 4 + 3][row] = a.w;
        }
        {
            int rowk = tid >> 4, c4 = tid & 15;
            int cbase = n0 + c4 * 4;
            const float* wp = W + (size_t)(k0 + rowk) * NC + cbase;
#pragma unroll
            for (int j = 0; j < 4; j++)
                Bs[rowk][c4 * 4 + j] = (cbase + j < NC) ? wp[j] : 0.0f;
        }
        __syncthreads();
#pragma unroll
        for (int kk = 0; kk < 16; kk++) {
            float a[4], bb[4];
#pragma unroll
            for (int i = 0; i < 4; i++) a[i] = As[kk][ty * 4 + i];
#pragma unroll
            for (int j = 0; j < 4; j++) bb[j] = Bs[kk][tx * 4 + j];
#pragma unroll
            for (int i = 0; i < 4; i++)
#pragma unroll
                for (int j = 0; j < 4; j++) accB[i][j] = fmaf(a[i], bb[j], accB[i][j]);
        }
        __syncthreads();
    }
#pragma unroll
    for (int i = 0; i < 4; i++) {
        int r = m0 + ty * 4 + i;
#pragma unroll
        for (int j = 0; j < 4; j++) {
            int c = n0 + tx * 4 + j;
            if (c < NC) {
                float s = accT[i][j] + accB[i][j];
                z[(size_t)r * NC + c] = s + bias[c];
            }
        }
    }
}

// ---------------- per-row stats ----------------
__global__ __launch_bounds__(256) void k_rowstats(const float* __restrict__ z,
                                                  int* __restrict__ y,
                                                  float* __restrict__ ptrg,
                                                  float* __restrict__ se,
                                                  float* __restrict__ rm,
                                                  int* __restrict__ am) {
    __shared__ float sv[256];
    __shared__ int si[256];
    const int tid = threadIdx.x, row = blockIdx.x;
    const float* zr = z + (size_t)row * NC;
    float bv = -INFINITY;
    int bi = 0x7fffffff;
    for (int c = tid; c < NC; c += 256) {
        float zz = zr[c];
        if (zz > bv) { bv = zz; bi = c; }
    }
    sv[tid] = bv; si[tid] = bi;
    __syncthreads();
    for (int s = 128; s > 0; s >>= 1) {
        if (tid < s) {
            float v2 = sv[tid + s]; int i2 = si[tid + s];
            if (v2 > sv[tid] || (v2 == sv[tid] && i2 < si[tid])) { sv[tid] = v2; si[tid] = i2; }
        }
        __syncthreads();
    }
    const float rmx = sv[0];
    const int amx = si[0];
    __syncthreads();
    float sl = 0.0f;
    for (int c = tid; c < NC; c += 256) sl += expf(zr[c] - rmx);
    sv[tid] = sl;
    __syncthreads();
    for (int s = 128; s > 0; s >>= 1) {
        if (tid < s) sv[tid] += sv[tid + s];
        __syncthreads();
    }
    if (tid == 0) {
        float s0 = sv[0];
        y[row] = amx; ptrg[row] = 1.0f / s0;
        se[row] = s0; rm[row] = rmx; am[row] = amx;
    }
}

__global__ void k_hist(const int* __restrict__ y, int* __restrict__ cnt) {
    int i = blockIdx.x * 256 + threadIdx.x;
    if (i < NB) atomicAdd(&cnt[y[i]], 1);
}
__global__ __launch_bounds__(1024) void k_group(const int* __restrict__ y,
                                                const int* __restrict__ cnt,
                                                int* __restrict__ off,
                                                int* __restrict__ pos,
                                                int* __restrict__ jidx,
                                                int* __restrict__ pinv) {
    __shared__ int s[1024];
    const int tid = threadIdx.x;
    int myc = (tid < NC) ? cnt[tid] : 0;
    s[tid] = myc;
    __syncthreads();
    for (int d = 1; d < 1024; d <<= 1) {
        int add = (tid >= d) ? s[tid - d] : 0;
        __syncthreads();
        s[tid] += add;
        __syncthreads();
    }
    if (tid < NC) {
        int excl = s[tid] - myc;
        off[tid] = excl;
        pos[tid] = excl;
    }
    if (tid == 0) off[NC] = NB;
    __syncthreads();
    for (int j = tid; j < NB; j += 1024) {
        int c = y[j];
        int p = atomicAdd(&pos[c], 1);
        jidx[p] = j;
        pinv[j] = p;
    }
}

// tz + initial permuted tu; u init lives in registers inside k_adam (reads z directly)
__global__ __launch_bounds__(256) void k_preptz(const float* __restrict__ z,
                                                const int* __restrict__ cnt,
                                                const int* __restrict__ pinv,
                                                float* __restrict__ tz,
                                                float* __restrict__ tuP) {
    __shared__ float sv[256];
    const int tid = threadIdx.x, row = blockIdx.x;
    const float* zr = z + (size_t)row * NC;
    float tm = -1000.0f;
    for (int c = tid; c < NC; c += 256) {
        float zz = zr[c];
        if (cnt[c] == 0) tm = fmaxf(tm, zz);
    }
    sv[tid] = tm;
    __syncthreads();
    for (int s = 128; s > 0; s >>= 1) {
        if (tid < s) sv[tid] = fmaxf(sv[tid], sv[tid + s]);
        __syncthreads();
    }
    if (tid == 0) { tz[row] = sv[0]; tuP[pinv[row]] = sv[0]; }
}

__global__ __launch_bounds__(256) void k_thr(const float* __restrict__ z,
                                             const float* __restrict__ tz,
                                             const int* __restrict__ y,
                                             const int* __restrict__ jidx,
                                             float* __restrict__ ThrG) {
    const int tid = threadIdx.x, a = blockIdx.x;
    const float PIF = 3.14159265358979323846f;
    const float* zr = z + (size_t)a * NC;
    for (int p = tid; p < NB; p += 256) {
        int j = jidx[p];
        int c = y[j];
        float L = zr[c] - tz[j];
        float q = L / 6.0f;
        float fq = floorf(q);
        float fh = fq + 0.5f;
        float latr = fh * 6.0f;
        float d1 = L - latr;
        float d2 = 2.0f * d1;
        float d3 = d2 / 6.0f;
        float d4 = 1.0f - d3;
        float d5 = PIF * d4;
        float sn = sinf(d5);
        float p6 = 6.0f * sn;
        float thr = L - p6;
        ThrG[(size_t)a * NB + p] = thr;
    }
}

// -------- agent-scope (device-coherent, L2-bypass) access helpers --------
__device__ __forceinline__ float ldgA(const float* p) {
    return __hip_atomic_load(p, __ATOMIC_RELAXED, __HIP_MEMORY_SCOPE_AGENT);
}
__device__ __forceinline__ int ldgAi(const int* p) {
    return __hip_atomic_load(p, __ATOMIC_RELAXED, __HIP_MEMORY_SCOPE_AGENT);
}
__device__ __forceinline__ void stgA(float* p, float v) {
    __hip_atomic_store(p, v, __ATOMIC_RELAXED, __HIP_MEMORY_SCOPE_AGENT);
}
__device__ __forceinline__ void stgAi(int* p, int v) {
    __hip_atomic_store(p, v, __ATOMIC_RELAXED, __HIP_MEMORY_SCOPE_AGENT);
}

// ---------------- all 100 Adam steps in one persistent kernel ----------------
// One row per block, 32 waves/CU. No threadfences: mutable cross-step state goes
// through agent-scope atomics (coherence point), constants stay L2-cached.
__global__ __launch_bounds__(256, 8) void k_adam(
    const float* __restrict__ z0,
    float* __restrict__ uout,
    const float* __restrict__ ThrG,
    const float* __restrict__ ptrg,
    const int* __restrict__ cnt,
    const int* __restrict__ off,
    const int* __restrict__ jidx,
    const int* __restrict__ pinv,
    float* __restrict__ seA, float* __restrict__ rmA,
    float* __restrict__ tuPA, int* __restrict__ amA,
    float* __restrict__ seB, float* __restrict__ rmB,
    float* __restrict__ tuPB, int* __restrict__ amB,
    const float* __restrict__ bcT,
    int* __restrict__ barLeaf, int* __restrict__ barRoot) {
    __shared__ float tuL[NB];    // permuted tu, staged coalesced
    __shared__ float thrL[NB];   // this row of ThrG, staged coalesced
    __shared__ float sv[256];
    __shared__ int si[256];
    __shared__ float fbc[2];
    __shared__ int ibc[1];
    const int tid = threadIdx.x;
    const int row = blockIdx.x;
    const size_t tbase = (size_t)row * NB;
    const float B1F = 0.9f;
    const float C1 = (float)(1.0 - 0.9);
    const float B2F = 0.999f;
    const float C2 = (float)(1.0 - 0.999);

    float U[4], M[4], V[4];
    {
        const size_t base = (size_t)row * NC;
#pragma unroll
        for (int k2 = 0; k2 < 4; k2++) {
            int c = tid + k2 * 256;
            U[k2] = (c < NC) ? z0[base + c] : 0.0f;
            M[k2] = 0.0f;
            V[k2] = 0.0f;
        }
    }
    const int myPinv = pinv[row];

    for (int t = 1; t <= 100; t++) {
        const bool odd = (t & 1);
        const float* seO = odd ? seA : seB;
        const float* rmO = odd ? rmA : rmB;
        const float* tuPO = odd ? tuPA : tuPB;
        const int*   amO = odd ? amA : amB;
        float* seN = odd ? seB : seA;
        float* rmN = odd ? rmB : rmA;
        float* tuPN = odd ? tuPB : tuPA;
        int*   amN = odd ? amB : amA;
        const float bc1 = bcT[2 * (t - 1)];
        const float bc2 = bcT[2 * (t - 1) + 1];

        // ---- stage mutable tu (agent loads) + constant ThrG row (cached) into LDS ----
        for (int p = tid; p < NB; p += 256) {
            tuL[p] = ldgA(&tuPO[p]);
            thrL[p] = ThrG[tbase + p];
        }

        // ---- global pmax / istar (identical scan + tree as before) ----
        float bv = -INFINITY;
        int bi = 0x7fffffff;
        for (int i = tid; i < NB; i += 256) {
            float pp = 1.0f / ldgA(&seO[i]);
            if (pp > bv || (pp == bv && i < bi)) { bv = pp; bi = i; }
        }
        sv[tid] = bv; si[tid] = bi;
        __syncthreads();
        for (int s = 128; s > 0; s >>= 1) {
            if (tid < s) {
                float v2 = sv[tid + s]; int i2 = si[tid + s];
                if (v2 > sv[tid] || (v2 == sv[tid] && i2 < si[tid])) { sv[tid] = v2; si[tid] = i2; }
            }
            __syncthreads();
        }
        const float pmax = sv[0];
        const int istar = si[0];
        __syncthreads();
        float s2l = 0.0f;
        for (int i = tid; i < NB; i += 256) {
            float d = pmax - ptrg[i];
            s2l += (d >= 0.0f) ? 1.0f : -1.0f;
        }
        sv[tid] = s2l;
        __syncthreads();
        for (int s = 128; s > 0; s >>= 1) {
            if (tid < s) sv[tid] += sv[tid + s];
            __syncthreads();
        }
        const float s2 = sv[0];
        if (tid == 0) {
            fbc[0] = ldgA(&seO[istar]);
            fbc[1] = ldgA(&rmO[istar]);
            ibc[0] = ldgAi(&amO[istar]);
        }
        __syncthreads();
        const float se_i = fbc[0], rm_i = fbc[1];
        const int jstar = ibc[0];
        const float Kf = 5.0f * (2048.0f * s2);
        const float coef = Kf * pmax;
        const bool ig2 = (row == istar);

        // ---- gradient + Adam update (registers; LDS-only inner loop) ----
        float nmax = -INFINITY;
        int nidx = 0x7fffffff;
        float ntop = -1000.0f;
#pragma unroll
        for (int k2 = 0; k2 < 4; k2++) {
            int c = tid + k2 * 256;
            if (c < NC) {
                float u0 = U[k2];
                float mm = M[k2];
                float vv = V[k2];
                int cn = cnt[c];
                int p0 = off[c], p1 = off[c + 1];
                float g = 0.0f;
                for (int p = p0; p < p1; p++) {
                    float marg = u0 - tuL[p];
                    float diff = marg - thrL[p];
                    g += (diff >= 0.0f) ? 1.0f : -1.0f;
                }
                if (ig2) {
                    float e = expf(u0 - rm_i);
                    float S = e / se_i;
                    float dlt = ((c == jstar) ? 1.0f : 0.0f) - S;
                    float t2v = coef * dlt;
                    g = g + t2v;
                }
                float t1m = B1F * mm;
                float t2m = C1 * g;
                mm = t1m + t2m;
                float gg1 = C2 * g;
                float gg2 = gg1 * g;
                float t1v = B2F * vv;
                vv = t1v + gg2;
                float mh = mm / bc1;
                float vh = vv / bc2;
                float num = 0.1f * mh;
                float sq = sqrtf(vh);
                float den = sq + 1e-8f;
                float qq = num / den;
                u0 = u0 - qq;
                U[k2] = u0;
                M[k2] = mm;
                V[k2] = vv;
                if (u0 > nmax || (u0 == nmax && c < nidx)) { nmax = u0; nidx = c; }
                if (cn == 0) ntop = fmaxf(ntop, u0);
            }
        }
        __syncthreads();
        sv[tid] = nmax; si[tid] = nidx;
        __syncthreads();
        for (int s = 128; s > 0; s >>= 1) {
            if (tid < s) {
                float v2 = sv[tid + s]; int i2 = si[tid + s];
                if (v2 > sv[tid] || (v2 == sv[tid] && i2 < si[tid])) { sv[tid] = v2; si[tid] = i2; }
            }
            __syncthreads();
        }
        const float rm_n = sv[0];
        const int am_n = si[0];
        __syncthreads();
        sv[tid] = ntop;
        __syncthreads();
        for (int s = 128; s > 0; s >>= 1) {
            if (tid < s) sv[tid] = fmaxf(sv[tid], sv[tid + s]);
            __syncthreads();
        }
        const float tu_n = sv[0];
        __syncthreads();
        float sel = 0.0f;
#pragma unroll
        for (int k2 = 0; k2 < 4; k2++) {
            int c = tid + k2 * 256;
            if (c < NC) sel += expf(U[k2] - rm_n);
        }
        sv[tid] = sel;
        __syncthreads();
        for (int s = 128; s > 0; s >>= 1) {
            if (tid < s) sv[tid] += sv[tid + s];
            __syncthreads();
        }
        if (tid == 0) {
            stgA(&seN[row], sv[0]);
            stgA(&rmN[row], rm_n);
            stgA(&tuPN[myPinv], tu_n);
            stgAi(&amN[row], am_n);
        }

        // ---- two-level grid barrier (no L2 flush; outputs already at coherence pt) ----
        if (t < 100) {
            __syncthreads();
            if (tid == 0) {
                asm volatile("s_waitcnt vmcnt(0)" ::: "memory");
                int lidx = (t - 1) * 64 + (row >> 5);
                int old = __hip_atomic_fetch_add(&barLeaf[lidx], 1,
                                                 __ATOMIC_RELAXED, __HIP_MEMORY_SCOPE_AGENT);
                if (old == 31) {
                    __hip_atomic_fetch_add(&barRoot[t - 1], 1,
                                           __ATOMIC_RELAXED, __HIP_MEMORY_SCOPE_AGENT);
                }
                int polls = 0;
                while (__hip_atomic_load(&barRoot[t - 1], __ATOMIC_RELAXED,
                                         __HIP_MEMORY_SCOPE_AGENT) < 64) {
                    __builtin_amdgcn_s_sleep(8);
                    if (++polls > 100000) break;   // fail visibly, never hang
                }
            }
            __syncthreads();
        }
    }

    {
        const size_t base = (size_t)row * NC;
#pragma unroll
        for (int k2 = 0; k2 < 4; k2++) {
            int c = tid + k2 * 256;
            if (c < NC) uout[base + c] = U[k2];
        }
    }
}

// ---------------- fuse: out = A + clamp(median5(A,P1..P4) - A, +-0.08) ----------------
__global__ void k_fuse5(const float* __restrict__ a, const float* __restrict__ p1,
                        const float* __restrict__ p2, const float* __restrict__ p3,
                        const float* __restrict__ p4, float* __restrict__ out, int n) {
    const float CL = 0.08f;
    int i = blockIdx.x * 256 + threadIdx.x;
    if (i < n) {
        float v0 = a[i], v1 = p1[i], v2 = p2[i], v3 = p3[i], v4 = p4[i];
        float vv[5] = {v0, v1, v2, v3, v4};
#pragma unroll
        for (int k = 1; k < 5; k++) {
            float key = vv[k];
            int j = k - 1;
            while (j >= 0 && vv[j] > key) { vv[j + 1] = vv[j]; j--; }
            vv[j + 1] = key;
        }
        float med = vv[2];
        float d = med - v0;
        d = fminf(fmaxf(d, -CL), CL);
        out[i] = v0 + d;
    }
}

extern "C" void kernel_launch(void* const* d_in, const int* in_sizes, int n_in,
                              void* d_out, int out_size, void* d_ws, size_t ws_size,
                              hipStream_t stream) {
    (void)in_sizes; (void)n_in; (void)out_size; (void)ws_size;
    const float* x = (const float*)d_in[0];
    const float* W = (const float*)d_in[1];
    const float* bias = (const float*)d_in[2];
    float* out = (float*)d_out;

    const size_t NE = (size_t)NB * NC;
    float* zm   = (float*)d_ws;
    float* t0   = zm + NE;                  // 5 trajectory buffers
    float* t1   = t0 + NE;
    float* t2   = t1 + NE;
    float* t3   = t2 + NE;
    float* t4   = t3 + NE;
    float* ThrG = t4 + NE;                  // 2048*2048
    float* tz   = ThrG + (size_t)NB * NB;
    float* ptrg = tz + NB;
    float* seA  = ptrg + NB;
    float* rmA  = seA + NB;
    float* tuPA = rmA + NB;
    float* seB  = tuPA + NB;
    float* rmB  = seB + NB;
    float* tuPB = rmB + NB;
    float* bcT  = tuPB + NB;                // 200 floats (bias-correction table)
    int* amA  = (int*)(bcT + 256);
    int* amB  = amA + NB;
    int* yv   = amB + NB;
    int* jidx = yv + NB;
    int* pinv = jidx + NB;
    int* cnt  = pinv + NB;
    int* off  = cnt + 1024;
    int* pos  = off + 1024;
    int* barRoot = pos + 1024;              // 128 ints
    int* barLeaf = barRoot + 128;           // 64*100 ints

    // host-side bias corrections, exact same powf as round-0 (host libm)
    static float h_bc[200];
    static int bc_init = 0;
    if (!bc_init) {
        for (int t = 1; t <= 100; t++) {
            h_bc[2 * (t - 1)]     = 1.0f - powf(0.9f, (float)t);
            h_bc[2 * (t - 1) + 1] = 1.0f - powf(0.999f, (float)t);
        }
        bc_init = 1;
    }
    hipMemcpyAsync(bcT, h_bc, 200 * sizeof(float), hipMemcpyHostToDevice, stream);

    float* traj[5] = {t0, t1, t2, t3, t4};
    const int PCs[5] = {0, 32, 24, 16, 10};   // monolithic, Kc=512,384,256,160
    const int nblk = (int)((NE + 255) / 256);

    for (int pass = 0; pass < 5; pass++) {
        k_gemm<<<dim3(16, 32), 256, 0, stream>>>(x, W, bias, zm, PCs[pass]);
        hipMemsetAsync(cnt, 0, 1024 * sizeof(int), stream);
        hipMemsetAsync(barRoot, 0, (128 + 64 * 100) * sizeof(int), stream);
        k_rowstats<<<NB, 256, 0, stream>>>(zm, yv, ptrg, seA, rmA, amA);
        k_hist<<<8, 256, 0, stream>>>(yv, cnt);
        k_group<<<1, 1024, 0, stream>>>(yv, cnt, off, pos, jidx, pinv);
        k_preptz<<<NB, 256, 0, stream>>>(zm, cnt, pinv, tz, tuPA);
        k_thr<<<NB, 256, 0, stream>>>(zm, tz, yv, jidx, ThrG);

        k_adam<<<NBLK, 256, 0, stream>>>(zm, traj[pass], ThrG, ptrg, cnt, off, jidx, pinv,
                                         seA, rmA, tuPA, amA, seB, rmB, tuPB, amB,
                                         bcT, barLeaf, barRoot);
    }

    k_fuse5<<<nblk, 256, 0, stream>>>(t0, t1, t2, t3, t4, out, (int)NE);
}

// Round 4
// 14690.327 us; speedup vs baseline: 2.0747x; 1.1994x over previous
//
#include <hip/hip_runtime.h>
#include <math.h>

#pragma clang fp contract(off)

#define NB 2048
#define NC 1000
#define NK 2048
#define NBLK 2048            // one block per row; 8 blocks/CU * 256 CUs co-resident

// ---------------- GEMM: fp32 fold-left ascending-k with K-panel folds of PC chunks ------
__global__ __launch_bounds__(256) void k_gemm(const float* __restrict__ x,
                                              const float* __restrict__ W,
                                              const float* __restrict__ bias,
                                              float* __restrict__ z, int PC) {
    __shared__ float As[16][64];
    __shared__ float Bs[16][64];
    const int tid = threadIdx.x;
    const int m0 = blockIdx.y * 64, n0 = blockIdx.x * 64;
    const int tx = tid & 15, ty = tid >> 4;
    float accT[4][4];
    float accB[4][4];
#pragma unroll
    for (int i = 0; i < 4; i++)
#pragma unroll
        for (int j = 0; j < 4; j++) { accT[i][j] = 0.0f; accB[i][j] = 0.0f; }

    for (int kb = 0; kb < 128; kb++) {
        if (PC > 0 && kb > 0 && (kb % PC) == 0) {
#pragma unroll
            for (int i = 0; i < 4; i++)
#pragma unroll
                for (int j = 0; j < 4; j++) { accT[i][j] += accB[i][j]; accB[i][j] = 0.0f; }
        }
        const int k0 = kb * 16;
        {
            int row = tid >> 2, kg = tid & 3;
            const float4 a = *(const float4*)(x + (size_t)(m0 + row) * NK + k0 + kg * 4);
            As[kg * 4 + 0][row] = a.x;
            As[kg * 4 + 1][row] = a.y;
            As[kg * 4 + 2][row] = a.z;
            As[kg * 4 + 3][row] = a.w;
        }
        {
            int rowk = tid >> 4, c4 = tid & 15;
            int cbase = n0 + c4 * 4;
            const float* wp = W + (size_t)(k0 + rowk) * NC + cbase;
#pragma unroll
            for (int j = 0; j < 4; j++)
                Bs[rowk][c4 * 4 + j] = (cbase + j < NC) ? wp[j] : 0.0f;
        }
        __syncthreads();
#pragma unroll
        for (int kk = 0; kk < 16; kk++) {
            float a[4], bb[4];
#pragma unroll
            for (int i = 0; i < 4; i++) a[i] = As[kk][ty * 4 + i];
#pragma unroll
            for (int j = 0; j < 4; j++) bb[j] = Bs[kk][tx * 4 + j];
#pragma unroll
            for (int i = 0; i < 4; i++)
#pragma unroll
                for (int j = 0; j < 4; j++) accB[i][j] = fmaf(a[i], bb[j], accB[i][j]);
        }
        __syncthreads();
    }
#pragma unroll
    for (int i = 0; i < 4; i++) {
        int r = m0 + ty * 4 + i;
#pragma unroll
        for (int j = 0; j < 4; j++) {
            int c = n0 + tx * 4 + j;
            if (c < NC) {
                float s = accT[i][j] + accB[i][j];
                z[(size_t)r * NC + c] = s + bias[c];
            }
        }
    }
}

// ---------------- per-row stats ----------------
__global__ __launch_bounds__(256) void k_rowstats(const float* __restrict__ z,
                                                  int* __restrict__ y,
                                                  float* __restrict__ ptrg,
                                                  float* __restrict__ se,
                                                  float* __restrict__ rm,
                                                  int* __restrict__ am) {
    __shared__ float sv[256];
    __shared__ int si[256];
    const int tid = threadIdx.x, row = blockIdx.x;
    const float* zr = z + (size_t)row * NC;
    float bv = -INFINITY;
    int bi = 0x7fffffff;
    for (int c = tid; c < NC; c += 256) {
        float zz = zr[c];
        if (zz > bv) { bv = zz; bi = c; }
    }
    sv[tid] = bv; si[tid] = bi;
    __syncthreads();
    for (int s = 128; s > 0; s >>= 1) {
        if (tid < s) {
            float v2 = sv[tid + s]; int i2 = si[tid + s];
            if (v2 > sv[tid] || (v2 == sv[tid] && i2 < si[tid])) { sv[tid] = v2; si[tid] = i2; }
        }
        __syncthreads();
    }
    const float rmx = sv[0];
    const int amx = si[0];
    __syncthreads();
    float sl = 0.0f;
    for (int c = tid; c < NC; c += 256) sl += expf(zr[c] - rmx);
    sv[tid] = sl;
    __syncthreads();
    for (int s = 128; s > 0; s >>= 1) {
        if (tid < s) sv[tid] += sv[tid + s];
        __syncthreads();
    }
    if (tid == 0) {
        float s0 = sv[0];
        y[row] = amx; ptrg[row] = 1.0f / s0;
        se[row] = s0; rm[row] = rmx; am[row] = amx;
    }
}

__global__ void k_hist(const int* __restrict__ y, int* __restrict__ cnt) {
    int i = blockIdx.x * 256 + threadIdx.x;
    if (i < NB) atomicAdd(&cnt[y[i]], 1);
}
__global__ __launch_bounds__(1024) void k_group(const int* __restrict__ y,
                                                const int* __restrict__ cnt,
                                                int* __restrict__ off,
                                                int* __restrict__ pos,
                                                int* __restrict__ jidx,
                                                int* __restrict__ pinv) {
    __shared__ int s[1024];
    const int tid = threadIdx.x;
    int myc = (tid < NC) ? cnt[tid] : 0;
    s[tid] = myc;
    __syncthreads();
    for (int d = 1; d < 1024; d <<= 1) {
        int add = (tid >= d) ? s[tid - d] : 0;
        __syncthreads();
        s[tid] += add;
        __syncthreads();
    }
    if (tid < NC) {
        int excl = s[tid] - myc;
        off[tid] = excl;
        pos[tid] = excl;
    }
    if (tid == 0) off[NC] = NB;
    __syncthreads();
    for (int j = tid; j < NB; j += 1024) {
        int c = y[j];
        int p = atomicAdd(&pos[c], 1);
        jidx[p] = j;
        pinv[j] = p;
    }
}

// tz + initial permuted tu
__global__ __launch_bounds__(256) void k_preptz(const float* __restrict__ z,
                                                const int* __restrict__ cnt,
                                                const int* __restrict__ pinv,
                                                float* __restrict__ tz,
                                                float* __restrict__ tuP) {
    __shared__ float sv[256];
    const int tid = threadIdx.x, row = blockIdx.x;
    const float* zr = z + (size_t)row * NC;
    float tm = -1000.0f;
    for (int c = tid; c < NC; c += 256) {
        float zz = zr[c];
        if (cnt[c] == 0) tm = fmaxf(tm, zz);
    }
    sv[tid] = tm;
    __syncthreads();
    for (int s = 128; s > 0; s >>= 1) {
        if (tid < s) sv[tid] = fmaxf(sv[tid], sv[tid + s]);
        __syncthreads();
    }
    if (tid == 0) { tz[row] = sv[0]; tuP[pinv[row]] = sv[0]; }
}

__global__ __launch_bounds__(256) void k_thr(const float* __restrict__ z,
                                             const float* __restrict__ tz,
                                             const int* __restrict__ y,
                                             const int* __restrict__ jidx,
                                             float* __restrict__ ThrG) {
    const int tid = threadIdx.x, a = blockIdx.x;
    const float PIF = 3.14159265358979323846f;
    const float* zr = z + (size_t)a * NC;
    for (int p = tid; p < NB; p += 256) {
        int j = jidx[p];
        int c = y[j];
        float L = zr[c] - tz[j];
        float q = L / 6.0f;
        float fq = floorf(q);
        float fh = fq + 0.5f;
        float latr = fh * 6.0f;
        float d1 = L - latr;
        float d2 = 2.0f * d1;
        float d3 = d2 / 6.0f;
        float d4 = 1.0f - d3;
        float d5 = PIF * d4;
        float sn = sinf(d5);
        float p6 = 6.0f * sn;
        float thr = L - p6;
        ThrG[(size_t)a * NB + p] = thr;
    }
}

// -------- agent-scope (device-coherent) access helpers --------
__device__ __forceinline__ float ldgA(const float* p) {
    return __hip_atomic_load(p, __ATOMIC_RELAXED, __HIP_MEMORY_SCOPE_AGENT);
}
__device__ __forceinline__ int ldgAi(const int* p) {
    return __hip_atomic_load(p, __ATOMIC_RELAXED, __HIP_MEMORY_SCOPE_AGENT);
}
__device__ __forceinline__ void stgA(float* p, float v) {
    __hip_atomic_store(p, v, __ATOMIC_RELAXED, __HIP_MEMORY_SCOPE_AGENT);
}
__device__ __forceinline__ void stgAi(int* p, int v) {
    __hip_atomic_store(p, v, __ATOMIC_RELAXED, __HIP_MEMORY_SCOPE_AGENT);
}

// ---------------- all 100 Adam steps in one persistent kernel ----------------
// Block 0 = reducer: publishes {coef, se_i, rm_i, jstar, istar} once per step;
// fan-out release (64 words, <=32 pollers each). thr row staged once per pass.
__global__ __launch_bounds__(256, 8) void k_adam(
    const float* __restrict__ z0,
    float* __restrict__ uout,
    const float* __restrict__ ThrG,
    const float* __restrict__ ptrg,
    const int* __restrict__ cnt,
    const int* __restrict__ off,
    const int* __restrict__ jidx,
    const int* __restrict__ pinv,
    float* __restrict__ seA, float* __restrict__ rmA,
    float* __restrict__ tuPA, int* __restrict__ amA,
    float* __restrict__ seB, float* __restrict__ rmB,
    float* __restrict__ tuPB, int* __restrict__ amB,
    const float* __restrict__ bcT,
    int* __restrict__ barLeaf, int* __restrict__ barRoot,
    int* __restrict__ leafRel,
    float* __restrict__ pubF, int* __restrict__ pubI) {
    __shared__ float tuLs[NB];   // permuted tu (restaged every step)
    __shared__ float thrL[NB];   // this row of ThrG (staged ONCE)
    __shared__ float sv[256];
    __shared__ int si[256];
    __shared__ float sc[4];      // coef, se_i, rm_i
    __shared__ int sci[2];       // jstar, istar
    __shared__ float outRmS;
    const int tid = threadIdx.x;
    const int row = blockIdx.x;
    const int leaf = row >> 5;
    const size_t tbase = (size_t)row * NB;
    const float B1F = 0.9f;
    const float C1 = (float)(1.0 - 0.9);
    const float B2F = 0.999f;
    const float C2 = (float)(1.0 - 0.999);

    float U[4], M[4], V[4];
    int cn_[4], p0_[4], p1_[4];
    {
        const size_t base = (size_t)row * NC;
#pragma unroll
        for (int k2 = 0; k2 < 4; k2++) {
            int c = tid + k2 * 256;
            if (c < NC) {
                U[k2] = z0[base + c];
                cn_[k2] = cnt[c];
                p0_[k2] = off[c];
                p1_[k2] = off[c + 1];
            } else {
                U[k2] = 0.0f; cn_[k2] = -1; p0_[k2] = 0; p1_[k2] = 0;
            }
            M[k2] = 0.0f;
            V[k2] = 0.0f;
        }
    }
    for (int p = tid; p < NB; p += 256) thrL[p] = ThrG[tbase + p];
    const int myPinv = pinv[row];

    for (int t = 1; t <= 100; t++) {
        const bool odd = (t & 1);
        const float* tuPO = odd ? tuPA : tuPB;
        float* seN = odd ? seB : seA;
        float* rmN = odd ? rmB : rmA;
        float* tuPN = odd ? tuPB : tuPA;
        int*   amN = odd ? amB : amA;
        const float bc1 = bcT[2 * (t - 1)];
        const float bc2 = bcT[2 * (t - 1) + 1];

        if (t == 1) {
            // initial step: per-block scan from prep-kernel arrays (identical math)
            for (int p = tid; p < NB; p += 256) tuLs[p] = ldgA(&tuPO[p]);
            float bv = -INFINITY;
            int bi = 0x7fffffff;
            for (int i = tid; i < NB; i += 256) {
                float pp = 1.0f / ldgA(&seA[i]);
                if (pp > bv || (pp == bv && i < bi)) { bv = pp; bi = i; }
            }
            sv[tid] = bv; si[tid] = bi;
            __syncthreads();
            for (int s = 128; s > 0; s >>= 1) {
                if (tid < s) {
                    float v2 = sv[tid + s]; int i2 = si[tid + s];
                    if (v2 > sv[tid] || (v2 == sv[tid] && i2 < si[tid])) { sv[tid] = v2; si[tid] = i2; }
                }
                __syncthreads();
            }
            const float pmax = sv[0];
            const int istar0 = si[0];
            __syncthreads();
            float s2l = 0.0f;
            for (int i = tid; i < NB; i += 256) {
                float d = pmax - ptrg[i];
                s2l += (d >= 0.0f) ? 1.0f : -1.0f;
            }
            sv[tid] = s2l;
            __syncthreads();
            for (int s = 128; s > 0; s >>= 1) {
                if (tid < s) sv[tid] += sv[tid + s];
                __syncthreads();
            }
            const float s2 = sv[0];
            if (tid == 0) {
                float Kf = 5.0f * (2048.0f * s2);
                float coef0 = Kf * pmax;
                sc[0] = coef0;
                sc[1] = ldgA(&seA[istar0]);
                sc[2] = ldgA(&rmA[istar0]);
                sci[0] = ldgAi(&amA[istar0]);
                sci[1] = istar0;
            }
            __syncthreads();
        } else {
            if (row != 0 && tid == 0) {
                int polls = 0;
                while (__hip_atomic_load(&leafRel[(t - 2) * 64 + leaf], __ATOMIC_RELAXED,
                                         __HIP_MEMORY_SCOPE_AGENT) == 0) {
                    __builtin_amdgcn_s_sleep(2);
                    if (++polls > (1 << 19)) break;   // fail visibly, never hang
                }
            }
            __syncthreads();
            if (row != 0 && tid == 0) {
                sc[0] = ldgA(&pubF[(t - 2) * 4 + 0]);
                sc[1] = ldgA(&pubF[(t - 2) * 4 + 1]);
                sc[2] = ldgA(&pubF[(t - 2) * 4 + 2]);
                sci[0] = ldgAi(&pubI[(t - 2) * 2 + 0]);
                sci[1] = ldgAi(&pubI[(t - 2) * 2 + 1]);
            }
            for (int p = tid; p < NB; p += 256) tuLs[p] = ldgA(&tuPO[p]);
            __syncthreads();
        }
        const float coef = sc[0], se_i = sc[1], rm_i = sc[2];
        const int jstar = sci[0], istar = sci[1];
        const bool ig2 = (row == istar);

        // ---- gradient + Adam update (registers; LDS-only inner loop) ----
        float nmax = -INFINITY;
        int nidx = 0x7fffffff;
        float ntop = -1000.0f;
#pragma unroll
        for (int k2 = 0; k2 < 4; k2++) {
            int c = tid + k2 * 256;
            if (c < NC) {
                float u0 = U[k2];
                float mm = M[k2];
                float vv = V[k2];
                float g = 0.0f;
                for (int p = p0_[k2]; p < p1_[k2]; p++) {
                    float marg = u0 - tuLs[p];
                    float diff = marg - thrL[p];
                    g += (diff >= 0.0f) ? 1.0f : -1.0f;
                }
                if (ig2) {
                    float e = expf(u0 - rm_i);
                    float S = e / se_i;
                    float dlt = ((c == jstar) ? 1.0f : 0.0f) - S;
                    float t2v = coef * dlt;
                    g = g + t2v;
                }
                float t1m = B1F * mm;
                float t2m = C1 * g;
                mm = t1m + t2m;
                float gg1 = C2 * g;
                float gg2 = gg1 * g;
                float t1v = B2F * vv;
                vv = t1v + gg2;
                float mh = mm / bc1;
                float vh = vv / bc2;
                float num = 0.1f * mh;
                float sq = sqrtf(vh);
                float den = sq + 1e-8f;
                float qq = num / den;
                u0 = u0 - qq;
                U[k2] = u0;
                M[k2] = mm;
                V[k2] = vv;
                if (u0 > nmax || (u0 == nmax && c < nidx)) { nmax = u0; nidx = c; }
                if (cn_[k2] == 0) ntop = fmaxf(ntop, u0);
            }
        }

        // ---- tree A: argmax (order-independent) — hybrid LDS+shfl ----
        float rm_n = 0.0f, tu_n = 0.0f, se_n = 0.0f;
        int am_n = 0;
        sv[tid] = nmax; si[tid] = nidx;
        __syncthreads();
        if (tid < 64) {
            float v = sv[tid]; int ix = si[tid];
            { float v2 = sv[tid + 128]; int i2 = si[tid + 128];
              if (v2 > v || (v2 == v && i2 < ix)) { v = v2; ix = i2; } }
            { float a = sv[tid + 64]; int ai = si[tid + 64];
              float b = sv[tid + 192]; int bi2 = si[tid + 192];
              if (b > a || (b == a && bi2 < ai)) { a = b; ai = bi2; }
              if (a > v || (a == v && ai < ix)) { v = a; ix = ai; } }
#pragma unroll
            for (int s = 32; s > 0; s >>= 1) {
                float v2 = __shfl_xor(v, s);
                int i2 = __shfl_xor(ix, s);
                if (v2 > v || (v2 == v && i2 < ix)) { v = v2; ix = i2; }
            }
            if (tid == 0) { outRmS = v; rm_n = v; am_n = ix; }
        }
        __syncthreads();
        const float rm_b = outRmS;
        // ---- tree B: masked max (order-independent) ----
        sv[tid] = ntop;
        __syncthreads();
        if (tid < 64) {
            float v = fmaxf(sv[tid], sv[tid + 128]);
            v = fmaxf(v, fmaxf(sv[tid + 64], sv[tid + 192]));
#pragma unroll
            for (int s = 32; s > 0; s >>= 1) v = fmaxf(v, __shfl_xor(v, s));
            if (tid == 0) tu_n = v;
        }
        __syncthreads();
        // ---- tree C: sel sum — hybrid fold reproduces exact pairwise tree order ----
        float sel = 0.0f;
#pragma unroll
        for (int k2 = 0; k2 < 4; k2++) {
            int c = tid + k2 * 256;
            if (c < NC) sel += expf(U[k2] - rm_b);
        }
        sv[tid] = sel;
        __syncthreads();
        if (tid < 64) {
            float v = (sv[tid] + sv[tid + 128]) + (sv[tid + 64] + sv[tid + 192]);
#pragma unroll
            for (int s = 32; s > 0; s >>= 1) v += __shfl_xor(v, s);
            if (tid == 0) se_n = v;
        }
        if (tid == 0) {
            stgA(&seN[row], se_n);
            stgA(&rmN[row], rm_n);
            stgA(&tuPN[myPinv], tu_n);
            stgAi(&amN[row], am_n);
            if (t < 100) {
                asm volatile("s_waitcnt vmcnt(0)" ::: "memory");
                int old = __hip_atomic_fetch_add(&barLeaf[(t - 1) * 64 + leaf], 1,
                                                 __ATOMIC_RELAXED, __HIP_MEMORY_SCOPE_AGENT);
                if (old == 31) {
                    __hip_atomic_fetch_add(&barRoot[t - 1], 1,
                                           __ATOMIC_RELAXED, __HIP_MEMORY_SCOPE_AGENT);
                }
            }
        }

        // ---- reducer: block 0 computes next step's global scalars, then releases ----
        if (row == 0 && t < 100) {
            if (tid == 0) {
                int polls = 0;
                while (__hip_atomic_load(&barRoot[t - 1], __ATOMIC_RELAXED,
                                         __HIP_MEMORY_SCOPE_AGENT) < 64) {
                    __builtin_amdgcn_s_sleep(2);
                    if (++polls > (1 << 19)) break;
                }
            }
            __syncthreads();
            const float* seW = odd ? seB : seA;
            const float* rmW = odd ? rmB : rmA;
            const int*   amW = odd ? amB : amA;
            float bv = -INFINITY;
            int bi = 0x7fffffff;
            for (int i = tid; i < NB; i += 256) {
                float pp = 1.0f / ldgA(&seW[i]);
                if (pp > bv || (pp == bv && i < bi)) { bv = pp; bi = i; }
            }
            sv[tid] = bv; si[tid] = bi;
            __syncthreads();
            for (int s = 128; s > 0; s >>= 1) {
                if (tid < s) {
                    float v2 = sv[tid + s]; int i2 = si[tid + s];
                    if (v2 > sv[tid] || (v2 == sv[tid] && i2 < si[tid])) { sv[tid] = v2; si[tid] = i2; }
                }
                __syncthreads();
            }
            const float pmax = sv[0];
            const int istarN = si[0];
            __syncthreads();
            float s2l = 0.0f;
            for (int i = tid; i < NB; i += 256) {
                float d = pmax - ptrg[i];
                s2l += (d >= 0.0f) ? 1.0f : -1.0f;
            }
            sv[tid] = s2l;
            __syncthreads();
            for (int s = 128; s > 0; s >>= 1) {
                if (tid < s) sv[tid] += sv[tid + s];
                __syncthreads();
            }
            const float s2 = sv[0];
            if (tid == 0) {
                float Kf = 5.0f * (2048.0f * s2);
                float coefN = Kf * pmax;
                float seI = ldgA(&seW[istarN]);
                float rmI = ldgA(&rmW[istarN]);
                int jstN = ldgAi(&amW[istarN]);
                sc[0] = coefN; sc[1] = seI; sc[2] = rmI;
                sci[0] = jstN; sci[1] = istarN;
                stgA(&pubF[(t - 1) * 4 + 0], coefN);
                stgA(&pubF[(t - 1) * 4 + 1], seI);
                stgA(&pubF[(t - 1) * 4 + 2], rmI);
                stgAi(&pubI[(t - 1) * 2 + 0], jstN);
                stgAi(&pubI[(t - 1) * 2 + 1], istarN);
                asm volatile("s_waitcnt vmcnt(0)" ::: "memory");
            }
            __syncthreads();
            if (tid < 64) stgAi(&leafRel[(t - 1) * 64 + tid], 1);
        }
    }

    {
        const size_t base = (size_t)row * NC;
#pragma unroll
        for (int k2 = 0; k2 < 4; k2++) {
            int c = tid + k2 * 256;
            if (c < NC) uout[base + c] = U[k2];
        }
    }
}

// ---------------- fuse: out = A + clamp(median5(A,P1..P4) - A, +-0.08) ----------------
__global__ void k_fuse5(const float* __restrict__ a, const float* __restrict__ p1,
                        const float* __restrict__ p2, const float* __restrict__ p3,
                        const float* __restrict__ p4, float* __restrict__ out, int n) {
    const float CL = 0.08f;
    int i = blockIdx.x * 256 + threadIdx.x;
    if (i < n) {
        float v0 = a[i], v1 = p1[i], v2 = p2[i], v3 = p3[i], v4 = p4[i];
        float vv[5] = {v0, v1, v2, v3, v4};
#pragma unroll
        for (int k = 1; k < 5; k++) {
            float key = vv[k];
            int j = k - 1;
            while (j >= 0 && vv[j] > key) { vv[j + 1] = vv[j]; j--; }
            vv[j + 1] = key;
        }
        float med = vv[2];
        float d = med - v0;
        d = fminf(fmaxf(d, -CL), CL);
        out[i] = v0 + d;
    }
}

extern "C" void kernel_launch(void* const* d_in, const int* in_sizes, int n_in,
                              void* d_out, int out_size, void* d_ws, size_t ws_size,
                              hipStream_t stream) {
    (void)in_sizes; (void)n_in; (void)out_size; (void)ws_size;
    const float* x = (const float*)d_in[0];
    const float* W = (const float*)d_in[1];
    const float* bias = (const float*)d_in[2];
    float* out = (float*)d_out;

    const size_t NE = (size_t)NB * NC;
    float* zm   = (float*)d_ws;
    float* t0   = zm + NE;                  // 5 trajectory buffers
    float* t1   = t0 + NE;
    float* t2   = t1 + NE;
    float* t3   = t2 + NE;
    float* t4   = t3 + NE;
    float* ThrG = t4 + NE;                  // 2048*2048
    float* tz   = ThrG + (size_t)NB * NB;
    float* ptrg = tz + NB;
    float* seA  = ptrg + NB;
    float* rmA  = seA + NB;
    float* tuPA = rmA + NB;
    float* seB  = tuPA + NB;
    float* rmB  = seB + NB;
    float* tuPB = rmB + NB;
    float* bcT  = tuPB + NB;                // 200 floats (bias-correction table)
    int* amA  = (int*)(bcT + 256);
    int* amB  = amA + NB;
    int* yv   = amB + NB;
    int* jidx = yv + NB;
    int* pinv = jidx + NB;
    int* cnt  = pinv + NB;
    int* off  = cnt + 1024;
    int* pos  = off + 1024;
    int* barRoot = pos + 1024;              // 128 ints
    int* barLeaf = barRoot + 128;           // 64*100 ints
    int* leafRel = barLeaf + 6400;          // 64*100 ints
    float* pubF  = (float*)(leafRel + 6400);  // 100*4 floats
    int*   pubI  = (int*)(pubF + 400);        // 100*2 ints

    // host-side bias corrections, exact same powf as round-0 (host libm)
    static float h_bc[200];
    static int bc_init = 0;
    if (!bc_init) {
        for (int t = 1; t <= 100; t++) {
            h_bc[2 * (t - 1)]     = 1.0f - powf(0.9f, (float)t);
            h_bc[2 * (t - 1) + 1] = 1.0f - powf(0.999f, (float)t);
        }
        bc_init = 1;
    }
    hipMemcpyAsync(bcT, h_bc, 200 * sizeof(float), hipMemcpyHostToDevice, stream);

    float* traj[5] = {t0, t1, t2, t3, t4};
    const int PCs[5] = {0, 32, 24, 16, 10};   // monolithic, Kc=512,384,256,160
    const int nblk = (int)((NE + 255) / 256);

    for (int pass = 0; pass < 5; pass++) {
        k_gemm<<<dim3(16, 32), 256, 0, stream>>>(x, W, bias, zm, PCs[pass]);
        hipMemsetAsync(cnt, 0, 1024 * sizeof(int), stream);
        hipMemsetAsync(barRoot, 0, (128 + 6400 + 6400) * sizeof(int), stream);
        k_rowstats<<<NB, 256, 0, stream>>>(zm, yv, ptrg, seA, rmA, amA);
        k_hist<<<8, 256, 0, stream>>>(yv, cnt);
        k_group<<<1, 1024, 0, stream>>>(yv, cnt, off, pos, jidx, pinv);
        k_preptz<<<NB, 256, 0, stream>>>(zm, cnt, pinv, tz, tuPA);
        k_thr<<<NB, 256, 0, stream>>>(zm, tz, yv, jidx, ThrG);

        k_adam<<<NBLK, 256, 0, stream>>>(zm, traj[pass], ThrG, ptrg, cnt, off, jidx, pinv,
                                         seA, rmA, tuPA, amA, seB, rmB, tuPB, amB,
                                         bcT, barLeaf, barRoot, leafRel, pubF, pubI);
    }

    k_fuse5<<<nblk, 256, 0, stream>>>(t0, t1, t2, t3, t4, out, (int)NE);
}